// Round 1
// baseline (389.343 us; speedup 1.0000x reference)
//
#include <hip/hip_runtime.h>

// ---------------------------------------------------------------------------
// LSTransformerEncoderLayer on MI355X (gfx950), round 0.
// B=16 S=512 H=1024 IMS=4096 NHEAD=16 d=64. fp32 in/out, bf16 MFMA compute.
// Structure: wconv -> LN1 -> QKV gemm -> fused attention -> proj gemm(+resid)
//            -> LN2 -> FFN1 gemm(relu) -> FFN2 gemm(+resid).
// GEMM: m97-style 128x128 tile, BK=64, global_load_lds(16B) with pre-swizzled
// source + XOR-swizzled ds_read_b128 (T2) for conflict-free fragment reads.
// ---------------------------------------------------------------------------

using f32x4 = __attribute__((ext_vector_type(4))) float;
using s16x8 = __attribute__((ext_vector_type(8))) short;   // 8 bf16 in 4 VGPRs
using i32x4 = __attribute__((ext_vector_type(4))) int;

__device__ __forceinline__ unsigned short f2bf(float f) {
    unsigned x = __builtin_bit_cast(unsigned, f);
    return (unsigned short)((x + 0x7fffu + ((x >> 16) & 1u)) >> 16);  // RNE
}

#define GLL16(gptr, lptr)                                                     \
    __builtin_amdgcn_global_load_lds(                                         \
        (const __attribute__((address_space(1))) void*)(gptr),                \
        (__attribute__((address_space(3))) void*)(lptr), 16, 0, 0)

// ---------------------------------------------------------------------------
// Weight convert: fp32 -> bf16, all four weights in one launch.
// seg sizes (float4): qkv_w 786432 | attn_ow 262144 | inter_w 1048576 | out_w 1048576
// ---------------------------------------------------------------------------
__global__ __launch_bounds__(256) void wconv_kernel(
    const float* __restrict__ w0, const float* __restrict__ w1,
    const float* __restrict__ w2, const float* __restrict__ w3,
    unsigned short* __restrict__ o0, unsigned short* __restrict__ o1,
    unsigned short* __restrict__ o2, unsigned short* __restrict__ o3) {
    long idx = (long)blockIdx.x * 256 + threadIdx.x;  // float4 index
    const float* src;
    unsigned short* dst;
    long rel;
    if (idx < 786432L)        { src = w0; dst = o0; rel = idx; }
    else if (idx < 1048576L)  { src = w1; dst = o1; rel = idx - 786432L; }
    else if (idx < 2097152L)  { src = w2; dst = o2; rel = idx - 1048576L; }
    else                      { src = w3; dst = o3; rel = idx - 2097152L; }
    float4 v = *(const float4*)(src + rel * 4);
    ushort4 o;
    o.x = f2bf(v.x); o.y = f2bf(v.y); o.z = f2bf(v.z); o.w = f2bf(v.w);
    *(ushort4*)(dst + rel * 4) = o;
}

// ---------------------------------------------------------------------------
// LayerNorm: one block per row of 1024 fp32, 256 threads (one float4 each).
// ---------------------------------------------------------------------------
__global__ __launch_bounds__(256) void ln_kernel(
    const float* __restrict__ x, const float* __restrict__ gw,
    const float* __restrict__ bw, unsigned short* __restrict__ y) {
    __shared__ float rbuf[8];
    const int row = blockIdx.x;
    const int t = threadIdx.x;
    const float* xr = x + (size_t)row * 1024;
    float4 v = *(const float4*)(xr + t * 4);
    float s  = v.x + v.y + v.z + v.w;
    float ss = v.x * v.x + v.y * v.y + v.z * v.z + v.w * v.w;
#pragma unroll
    for (int sh = 1; sh < 64; sh <<= 1) {
        s  += __shfl_xor(s, sh, 64);
        ss += __shfl_xor(ss, sh, 64);
    }
    int w = t >> 6;
    if ((t & 63) == 0) { rbuf[w * 2] = s; rbuf[w * 2 + 1] = ss; }
    __syncthreads();
    s  = rbuf[0] + rbuf[2] + rbuf[4] + rbuf[6];
    ss = rbuf[1] + rbuf[3] + rbuf[5] + rbuf[7];
    float mu  = s * (1.f / 1024.f);
    float var = ss * (1.f / 1024.f) - mu * mu;
    float rs  = rsqrtf(var + 1e-5f);
    float4 gv = *(const float4*)(gw + t * 4);
    float4 bv = *(const float4*)(bw + t * 4);
    ushort4 o;
    o.x = f2bf((v.x - mu) * rs * gv.x + bv.x);
    o.y = f2bf((v.y - mu) * rs * gv.y + bv.y);
    o.z = f2bf((v.z - mu) * rs * gv.z + bv.z);
    o.w = f2bf((v.w - mu) * rs * gv.w + bv.w);
    *(ushort4*)(y + (size_t)row * 1024 + t * 4) = o;
}

// ---------------------------------------------------------------------------
// GEMM C[M,N] = A[M,K] * B[N,K]^T (+bias, +resid, relu, out bf16/f32).
// 256 threads = 4 waves (2x2), wave tile 64x64 = 4x4 frags of 16x16, BK=64.
// LDS: As/Bs [128][64] bf16, physically XOR-swizzled: phys = lin ^ ((row&7)<<4).
// Staged with global_load_lds(16B): linear LDS dest, inverse-swizzled source.
// ---------------------------------------------------------------------------
template <bool RELU, bool RESID, bool OUT_BF16>
__global__ __launch_bounds__(256, 2) void gemm_bt(
    const unsigned short* __restrict__ A, const unsigned short* __restrict__ Bw,
    const float* __restrict__ bias, const float* __restrict__ resid,
    void* __restrict__ Cout, int M, int N, int K) {
    __shared__ char smem[2 * 128 * 64 * 2];
    char* As = smem;
    char* Bs = smem + 128 * 64 * 2;

    const int tid = threadIdx.x;
    const int lane = tid & 63;
    const int w = tid >> 6;
    const int wr = w >> 1, wc = w & 1;
    const int g = lane >> 4;
    const int fr = lane & 15;
    const int m0 = blockIdx.y * 128;
    const int n0 = blockIdx.x * 128;

    f32x4 acc[4][4] = {};

    for (int kt = 0; kt < K; kt += 64) {
#pragma unroll
        for (int c = 0; c < 4; ++c) {
            int lin = (c * 256 + tid) * 16;        // linear LDS byte (dest)
            int row = lin >> 7;                    // 128 B per row
            int Lb = lin ^ ((row & 7) << 4);       // logical byte (source)
            int colb = Lb & 127;
            const char* ga = (const char*)A + ((size_t)(m0 + row) * K + kt) * 2 + colb;
            const char* gb = (const char*)Bw + ((size_t)(n0 + row) * K + kt) * 2 + colb;
            GLL16(ga, As + lin);
            GLL16(gb, Bs + lin);
        }
        __syncthreads();
#pragma unroll
        for (int ks = 0; ks < 2; ++ks) {
            s16x8 af[4], bf[4];
#pragma unroll
            for (int mi = 0; mi < 4; ++mi) {
                int row = wr * 64 + mi * 16 + fr;
                int off = (row << 7) + ((ks * 64 + g * 16) ^ ((row & 7) << 4));
                af[mi] = *(const s16x8*)(As + off);
            }
#pragma unroll
            for (int ni = 0; ni < 4; ++ni) {
                int row = wc * 64 + ni * 16 + fr;
                int off = (row << 7) + ((ks * 64 + g * 16) ^ ((row & 7) << 4));
                bf[ni] = *(const s16x8*)(Bs + off);
            }
#pragma unroll
            for (int mi = 0; mi < 4; ++mi)
#pragma unroll
                for (int ni = 0; ni < 4; ++ni)
                    acc[mi][ni] = __builtin_amdgcn_mfma_f32_16x16x32_bf16(
                        af[mi], bf[ni], acc[mi][ni], 0, 0, 0);
        }
        __syncthreads();
    }

    float bv[4];
#pragma unroll
    for (int ni = 0; ni < 4; ++ni) bv[ni] = bias[n0 + wc * 64 + ni * 16 + fr];
#pragma unroll
    for (int mi = 0; mi < 4; ++mi) {
#pragma unroll
        for (int r = 0; r < 4; ++r) {
            int row = m0 + wr * 64 + mi * 16 + g * 4 + r;
#pragma unroll
            for (int ni = 0; ni < 4; ++ni) {
                int col = n0 + wc * 64 + ni * 16 + fr;
                float v = acc[mi][ni][r] + bv[ni];
                if (RELU) v = v > 0.f ? v : 0.f;
                if (RESID) v += resid[(size_t)row * N + col];
                if (OUT_BF16)
                    ((unsigned short*)Cout)[(size_t)row * N + col] = f2bf(v);
                else
                    ((float*)Cout)[(size_t)row * N + col] = v;
            }
        }
    }
}

// ---------------------------------------------------------------------------
// Fused attention: one workgroup per (b,h). K + transposed V staged in LDS
// (XOR-swizzled, conflict-reduced). 32 q-blocks of 16 rows, cooperative:
// scores wave-split over kpos, softmax cross-wave via LDS, P -> LDS, PV
// wave-split over d. qkv layout [B*S][3072]: q|k|v, head cols h*64..h*64+63.
// ---------------------------------------------------------------------------
__global__ __launch_bounds__(256) void attn_kernel(
    const unsigned short* __restrict__ qkv, const float* __restrict__ mask,
    unsigned short* __restrict__ ctx) {
    extern __shared__ char smem[];
    char* Ks = smem;                  // [512][64] bf16 swizzled, 64 KB
    char* Vt = smem + 65536;          // [64][512] bf16 (V^T) swizzled, 64 KB
    char* Pl = smem + 131072;         // [16][512] bf16 swizzled, 16 KB
    float* msk = (float*)(smem + 147456);  // 512 f32
    float* red = (float*)(smem + 149504);  // [4 waves][16 rows][m,l]

    const int tid = threadIdx.x;
    const int lane = tid & 63;
    const int w = tid >> 6;
    const int g = lane >> 4;
    const int fr = lane & 15;
    const int b = blockIdx.x >> 4;
    const int h = blockIdx.x & 15;

    const size_t rstr = 3072;
    const unsigned short* qbase = qkv + (size_t)b * 512 * rstr + h * 64;
    const unsigned short* kbase = qbase + 1024;
    const unsigned short* vbase = qbase + 2048;

    if (tid < 128) *(float4*)(msk + tid * 4) = *(const float4*)(mask + b * 512 + tid * 4);

    for (int p = 0; p < 16; ++p) {
        int s = p * 32 + (tid >> 3);
        int d0 = (tid & 7) * 8;
        i32x4 kv = *(const i32x4*)(kbase + (size_t)s * rstr + d0);
        *(i32x4*)(Ks + ((s * 128 + d0 * 2) ^ ((s & 7) << 4))) = kv;
        union { i32x4 v; unsigned short u[8]; } vu;
        vu.v = *(const i32x4*)(vbase + (size_t)s * rstr + d0);
#pragma unroll
        for (int j = 0; j < 8; ++j) {
            int d = d0 + j;
            *(unsigned short*)(Vt + ((d * 1024 + s * 2) ^ ((d & 7) << 4))) = vu.u[j];
        }
    }
    __syncthreads();

#pragma unroll 1
    for (int qb = 0; qb < 32; ++qb) {
        // Q fragments straight from global (L2-hot)
        s16x8 qf[2];
#pragma unroll
        for (int ks = 0; ks < 2; ++ks)
            qf[ks] = *(const s16x8*)(qbase + (size_t)(qb * 16 + fr) * rstr + ks * 32 + g * 8);

        // scores: D[q(reg)][kpos(lane&15)], this wave covers kpos w*128..+128
        f32x4 sc[8];
#pragma unroll
        for (int f = 0; f < 8; ++f) {
            int srow = w * 128 + f * 16 + fr;
            f32x4 a = {};
#pragma unroll
            for (int ks = 0; ks < 2; ++ks) {
                s16x8 kf = *(const s16x8*)(Ks + (srow * 128 + ((ks * 64 + g * 16) ^ ((srow & 7) << 4))));
                a = __builtin_amdgcn_mfma_f32_16x16x32_bf16(qf[ks], kf, a, 0, 0, 0);
            }
            sc[f] = a;
        }

        // scale + mask, per-row (rows 4g+r) local max
        float mloc[4] = {-3e38f, -3e38f, -3e38f, -3e38f};
#pragma unroll
        for (int f = 0; f < 8; ++f) {
            float mk = msk[w * 128 + f * 16 + fr];
#pragma unroll
            for (int r = 0; r < 4; ++r) {
                float v = sc[f][r] * 0.125f + mk;
                sc[f][r] = v;
                mloc[r] = fmaxf(mloc[r], v);
            }
        }
#pragma unroll
        for (int sh = 1; sh < 16; sh <<= 1)
#pragma unroll
            for (int r = 0; r < 4; ++r) mloc[r] = fmaxf(mloc[r], __shfl_xor(mloc[r], sh, 64));

        float lloc[4] = {0.f, 0.f, 0.f, 0.f};
#pragma unroll
        for (int f = 0; f < 8; ++f)
#pragma unroll
            for (int r = 0; r < 4; ++r) {
                float p = __expf(sc[f][r] - mloc[r]);
                sc[f][r] = p;
                lloc[r] += p;
            }
#pragma unroll
        for (int sh = 1; sh < 16; sh <<= 1)
#pragma unroll
            for (int r = 0; r < 4; ++r) lloc[r] += __shfl_xor(lloc[r], sh, 64);

        if (fr == 0) {
#pragma unroll
            for (int r = 0; r < 4; ++r) {
                red[(w * 16 + g * 4 + r) * 2]     = mloc[r];
                red[(w * 16 + g * 4 + r) * 2 + 1] = lloc[r];
            }
        }
        __syncthreads();

        // cross-wave combine (online-softmax merge)
        float lg[4], fac[4];
#pragma unroll
        for (int r = 0; r < 4; ++r) {
            int rowq = g * 4 + r;
            float m = red[rowq * 2];
#pragma unroll
            for (int w2 = 1; w2 < 4; ++w2) m = fmaxf(m, red[(w2 * 16 + rowq) * 2]);
            float l = 0.f;
#pragma unroll
            for (int w2 = 0; w2 < 4; ++w2)
                l += red[(w2 * 16 + rowq) * 2 + 1] * __expf(red[(w2 * 16 + rowq) * 2] - m);
            lg[r] = l;
            fac[r] = __expf(mloc[r] - m);
        }

        // write P (unnormalized, exp(s-m_global)) to LDS in A-operand layout
#pragma unroll
        for (int f = 0; f < 8; ++f)
#pragma unroll
            for (int r = 0; r < 4; ++r) {
                int q = g * 4 + r;
                int kp = w * 128 + f * 16 + fr;
                *(unsigned short*)(Pl + ((q * 1024 + kp * 2) ^ ((q & 7) << 4))) =
                    f2bf(sc[f][r] * fac[r]);
            }
        __syncthreads();

        // PV: this wave computes d-block w*16..w*16+15 over all 512 kpos
        f32x4 o = {};
#pragma unroll
        for (int ks = 0; ks < 16; ++ks) {
            s16x8 pf = *(const s16x8*)(Pl + (fr * 1024 + ((ks * 64 + g * 16) ^ ((fr & 7) << 4))));
            int vrow = w * 16 + fr;
            s16x8 vf = *(const s16x8*)(Vt + (vrow * 1024 + ((ks * 64 + g * 16) ^ ((vrow & 7) << 4))));
            o = __builtin_amdgcn_mfma_f32_16x16x32_bf16(pf, vf, o, 0, 0, 0);
        }
#pragma unroll
        for (int r = 0; r < 4; ++r) {
            int q = g * 4 + r;
            ctx[(size_t)(b * 512 + qb * 16 + q) * 1024 + h * 64 + w * 16 + fr] =
                f2bf(o[r] / lg[r]);
        }
        __syncthreads();
    }
}

// ---------------------------------------------------------------------------
// Launch. ws layout (bytes):
//   0          qkv bf16   [8192][3072]  50,331,648   (later overlaid by h)
//   50331648   y1 bf16    [8192][1024]  16,777,216   (h overlay tail)
//   67108864   ctx/y2 bf16[8192][1024]  16,777,216
//   83886080   x2 fp32    [8192][1024]  33,554,432
//   117440512  bf16 weights (qkv_w, attn_ow, inter_w, out_w) 25,165,824
//   total 142,606,336
// ---------------------------------------------------------------------------
extern "C" void kernel_launch(void* const* d_in, const int* in_sizes, int n_in,
                              void* d_out, int out_size, void* d_ws, size_t ws_size,
                              hipStream_t stream) {
    const float* x    = (const float*)d_in[0];
    const float* mask = (const float*)d_in[1];
    const float* qkvw = (const float*)d_in[2];
    const float* qkvb = (const float*)d_in[3];
    const float* ow   = (const float*)d_in[4];
    const float* ob   = (const float*)d_in[5];
    const float* ln1g = (const float*)d_in[6];
    const float* ln1b = (const float*)d_in[7];
    const float* iw   = (const float*)d_in[8];
    const float* ib   = (const float*)d_in[9];
    const float* o2w  = (const float*)d_in[10];
    const float* o2b  = (const float*)d_in[11];
    const float* ln2g = (const float*)d_in[12];
    const float* ln2b = (const float*)d_in[13];

    char* ws = (char*)d_ws;
    unsigned short* qkvbuf = (unsigned short*)(ws);
    unsigned short* ybuf   = (unsigned short*)(ws + 50331648);
    unsigned short* cbuf   = (unsigned short*)(ws + 67108864);
    float*          x2     = (float*)(ws + 83886080);
    unsigned short* wq     = (unsigned short*)(ws + 117440512);
    unsigned short* wo     = (unsigned short*)(ws + 123731968);
    unsigned short* wi     = (unsigned short*)(ws + 125829120);
    unsigned short* wo2    = (unsigned short*)(ws + 134217728);
    unsigned short* hbuf   = (unsigned short*)(ws);  // overlays qkvbuf+ybuf

    wconv_kernel<<<12288, 256, 0, stream>>>(qkvw, ow, iw, o2w, wq, wo, wi, wo2);
    ln_kernel<<<8192, 256, 0, stream>>>(x, ln1g, ln1b, ybuf);
    gemm_bt<false, false, true><<<dim3(24, 64), 256, 0, stream>>>(
        ybuf, wq, qkvb, nullptr, qkvbuf, 8192, 3072, 1024);
    hipFuncSetAttribute(reinterpret_cast<const void*>(attn_kernel),
                        hipFuncAttributeMaxDynamicSharedMemorySize, 150016);
    attn_kernel<<<256, 256, 150016, stream>>>(qkvbuf, mask, cbuf);
    gemm_bt<false, true, false><<<dim3(8, 64), 256, 0, stream>>>(
        cbuf, wo, ob, x, x2, 8192, 1024, 1024);
    ln_kernel<<<8192, 256, 0, stream>>>(x2, ln2g, ln2b, cbuf);
    gemm_bt<true, false, true><<<dim3(32, 64), 256, 0, stream>>>(
        cbuf, wi, ib, nullptr, hbuf, 8192, 4096, 1024);
    gemm_bt<false, true, false><<<dim3(8, 64), 256, 0, stream>>>(
        hbuf, wo2, o2b, x2, (float*)d_out, 8192, 1024, 4096);
}

// Round 2
// 307.562 us; speedup vs baseline: 1.2659x; 1.2659x over previous
//
#include <hip/hip_runtime.h>

// ---------------------------------------------------------------------------
// LSTransformerEncoderLayer on MI355X (gfx950), round 1.
// Round-1 change: attention rewritten — 32x32 MFMA, swapped QK^T (q lane-local
// softmax), in-register P via v_cvt_pk_bf16_f32 + v_permlane32_swap_b32,
// flash-style 128-kpos tiles, K(GLL+xor-swz)/V^T double-buffered in 64KB LDS,
// defer-max (THR=11 in log2 domain). GEMM/LN/wconv unchanged from round 0.
// ---------------------------------------------------------------------------

using f32x4  = __attribute__((ext_vector_type(4))) float;
using f32x16 = __attribute__((ext_vector_type(16))) float;
using s16x8  = __attribute__((ext_vector_type(8))) short;   // 8 bf16 in 4 VGPRs
using i32x4  = __attribute__((ext_vector_type(4))) int;

__device__ __forceinline__ unsigned short f2bf(float f) {
    unsigned x = __builtin_bit_cast(unsigned, f);
    return (unsigned short)((x + 0x7fffu + ((x >> 16) & 1u)) >> 16);  // RNE
}

#define GLL16(gptr, lptr)                                                     \
    __builtin_amdgcn_global_load_lds(                                         \
        (const __attribute__((address_space(1))) void*)(gptr),                \
        (__attribute__((address_space(3))) void*)(lptr), 16, 0, 0)

// ---------------------------------------------------------------------------
// Weight convert: fp32 -> bf16, all four weights in one launch.
// ---------------------------------------------------------------------------
__global__ __launch_bounds__(256) void wconv_kernel(
    const float* __restrict__ w0, const float* __restrict__ w1,
    const float* __restrict__ w2, const float* __restrict__ w3,
    unsigned short* __restrict__ o0, unsigned short* __restrict__ o1,
    unsigned short* __restrict__ o2, unsigned short* __restrict__ o3) {
    long idx = (long)blockIdx.x * 256 + threadIdx.x;  // float4 index
    const float* src;
    unsigned short* dst;
    long rel;
    if (idx < 786432L)        { src = w0; dst = o0; rel = idx; }
    else if (idx < 1048576L)  { src = w1; dst = o1; rel = idx - 786432L; }
    else if (idx < 2097152L)  { src = w2; dst = o2; rel = idx - 1048576L; }
    else                      { src = w3; dst = o3; rel = idx - 2097152L; }
    float4 v = *(const float4*)(src + rel * 4);
    ushort4 o;
    o.x = f2bf(v.x); o.y = f2bf(v.y); o.z = f2bf(v.z); o.w = f2bf(v.w);
    *(ushort4*)(dst + rel * 4) = o;
}

// ---------------------------------------------------------------------------
// LayerNorm: one block per row of 1024 fp32, 256 threads (one float4 each).
// ---------------------------------------------------------------------------
__global__ __launch_bounds__(256) void ln_kernel(
    const float* __restrict__ x, const float* __restrict__ gw,
    const float* __restrict__ bw, unsigned short* __restrict__ y) {
    __shared__ float rbuf[8];
    const int row = blockIdx.x;
    const int t = threadIdx.x;
    const float* xr = x + (size_t)row * 1024;
    float4 v = *(const float4*)(xr + t * 4);
    float s  = v.x + v.y + v.z + v.w;
    float ss = v.x * v.x + v.y * v.y + v.z * v.z + v.w * v.w;
#pragma unroll
    for (int sh = 1; sh < 64; sh <<= 1) {
        s  += __shfl_xor(s, sh, 64);
        ss += __shfl_xor(ss, sh, 64);
    }
    int w = t >> 6;
    if ((t & 63) == 0) { rbuf[w * 2] = s; rbuf[w * 2 + 1] = ss; }
    __syncthreads();
    s  = rbuf[0] + rbuf[2] + rbuf[4] + rbuf[6];
    ss = rbuf[1] + rbuf[3] + rbuf[5] + rbuf[7];
    float mu  = s * (1.f / 1024.f);
    float var = ss * (1.f / 1024.f) - mu * mu;
    float rs  = rsqrtf(var + 1e-5f);
    float4 gv = *(const float4*)(gw + t * 4);
    float4 bv = *(const float4*)(bw + t * 4);
    ushort4 o;
    o.x = f2bf((v.x - mu) * rs * gv.x + bv.x);
    o.y = f2bf((v.y - mu) * rs * gv.y + bv.y);
    o.z = f2bf((v.z - mu) * rs * gv.z + bv.z);
    o.w = f2bf((v.w - mu) * rs * gv.w + bv.w);
    *(ushort4*)(y + (size_t)row * 1024 + t * 4) = o;
}

// ---------------------------------------------------------------------------
// GEMM C[M,N] = A[M,K] * B[N,K]^T (+bias, +resid, relu, out bf16/f32).
// Unchanged from round 0 (passed).
// ---------------------------------------------------------------------------
template <bool RELU, bool RESID, bool OUT_BF16>
__global__ __launch_bounds__(256, 2) void gemm_bt(
    const unsigned short* __restrict__ A, const unsigned short* __restrict__ Bw,
    const float* __restrict__ bias, const float* __restrict__ resid,
    void* __restrict__ Cout, int M, int N, int K) {
    __shared__ char smem[2 * 128 * 64 * 2];
    char* As = smem;
    char* Bs = smem + 128 * 64 * 2;

    const int tid = threadIdx.x;
    const int lane = tid & 63;
    const int w = tid >> 6;
    const int wr = w >> 1, wc = w & 1;
    const int g = lane >> 4;
    const int fr = lane & 15;
    const int m0 = blockIdx.y * 128;
    const int n0 = blockIdx.x * 128;

    f32x4 acc[4][4] = {};

    for (int kt = 0; kt < K; kt += 64) {
#pragma unroll
        for (int c = 0; c < 4; ++c) {
            int lin = (c * 256 + tid) * 16;        // linear LDS byte (dest)
            int row = lin >> 7;                    // 128 B per row
            int Lb = lin ^ ((row & 7) << 4);       // logical byte (source)
            int colb = Lb & 127;
            const char* ga = (const char*)A + ((size_t)(m0 + row) * K + kt) * 2 + colb;
            const char* gb = (const char*)Bw + ((size_t)(n0 + row) * K + kt) * 2 + colb;
            GLL16(ga, As + lin);
            GLL16(gb, Bs + lin);
        }
        __syncthreads();
#pragma unroll
        for (int ks = 0; ks < 2; ++ks) {
            s16x8 af[4], bf[4];
#pragma unroll
            for (int mi = 0; mi < 4; ++mi) {
                int row = wr * 64 + mi * 16 + fr;
                int off = (row << 7) + ((ks * 64 + g * 16) ^ ((row & 7) << 4));
                af[mi] = *(const s16x8*)(As + off);
            }
#pragma unroll
            for (int ni = 0; ni < 4; ++ni) {
                int row = wc * 64 + ni * 16 + fr;
                int off = (row << 7) + ((ks * 64 + g * 16) ^ ((row & 7) << 4));
                bf[ni] = *(const s16x8*)(Bs + off);
            }
#pragma unroll
            for (int mi = 0; mi < 4; ++mi)
#pragma unroll
                for (int ni = 0; ni < 4; ++ni)
                    acc[mi][ni] = __builtin_amdgcn_mfma_f32_16x16x32_bf16(
                        af[mi], bf[ni], acc[mi][ni], 0, 0, 0);
        }
        __syncthreads();
    }

    float bv[4];
#pragma unroll
    for (int ni = 0; ni < 4; ++ni) bv[ni] = bias[n0 + wc * 64 + ni * 16 + fr];
#pragma unroll
    for (int mi = 0; mi < 4; ++mi) {
#pragma unroll
        for (int r = 0; r < 4; ++r) {
            int row = m0 + wr * 64 + mi * 16 + g * 4 + r;
#pragma unroll
            for (int ni = 0; ni < 4; ++ni) {
                int col = n0 + wc * 64 + ni * 16 + fr;
                float v = acc[mi][ni][r] + bv[ni];
                if (RELU) v = v > 0.f ? v : 0.f;
                if (RESID) v += resid[(size_t)row * N + col];
                if (OUT_BF16)
                    ((unsigned short*)Cout)[(size_t)row * N + col] = f2bf(v);
                else
                    ((float*)Cout)[(size_t)row * N + col] = v;
            }
        }
    }
}

// ---------------------------------------------------------------------------
// Fused attention v2. Grid = 512 blocks: blockIdx = bh*2 + qhalf.
// Block = 512 thr = 8 waves; wave owns 32 q-rows (q = lane&31, lane-local
// softmax). Flash loop over 4 kpos-tiles of 128.
// LDS (dynamic 64KB): K[2][128][64]bf16 xor-swz((row&7)<<4) @0/16384,
//                     V^T[2][64][128]bf16 xor-swz((d&15)<<4) @32768/49152.
// QK^T: S^T = mfma32(K, Q) -> lane holds row q=lane&31, kpos=(r&3)+8(r>>2)+
// 4*(lane>>5)+32t. P assembled in-register: cvt_pk_bf16 + permlane32_swap.
// PV: O += mfma32(P, V^T-read), O[q=(r&3)+8(r>>2)+4hi][d=dt*32+lane&31].
// ---------------------------------------------------------------------------
__global__ __launch_bounds__(512, 2) void attn_kernel(
    const unsigned short* __restrict__ qkv, const float* __restrict__ mask,
    unsigned short* __restrict__ ctx) {
    extern __shared__ char smem[];

    const int tid = threadIdx.x;
    const int lane = tid & 63;
    const int w = tid >> 6;
    const int l31 = lane & 31;
    const int hi = lane >> 5;
    const int bh = blockIdx.x >> 1;
    const int b = bh >> 4, h = bh & 15;
    const int qt = (blockIdx.x & 1) * 256 + w * 32;

    const size_t rstr = 3072;
    const unsigned short* qbase = qkv + (size_t)b * 512 * rstr + h * 64;
    const unsigned short* kbase = qbase + 1024;
    const unsigned short* vbase = qbase + 2048;
    const float* mrow = mask + b * 512;

    // Q fragments resident: B-operand, col=q=l31, k=(hi)*8+j within kc*16 chunk
    s16x8 qf[4];
#pragma unroll
    for (int kc = 0; kc < 4; ++kc)
        qf[kc] = *(const s16x8*)(qbase + (size_t)(qt + l31) * rstr + kc * 16 + hi * 8);

    f32x16 O0 = {}, O1 = {};
    float m = -3e38f, l = 0.f;
    const int bpbase = 36 * hi * 4;  // ds_bpermute byte base: lane (lane&32)+q'

    auto stage = [&](int kt, int bufsel) {
        char* Kb = smem + bufsel * 16384;
        char* Vb = smem + 32768 + bufsel * 16384;
#pragma unroll
        for (int c = 0; c < 2; ++c) {
            int lin = (c * 512 + tid) * 16;
            int row = lin >> 7;
            int colb = (lin & 127) ^ ((row & 7) << 4);
            GLL16((const char*)kbase + (size_t)(kt * 128 + row) * rstr * 2 + colb,
                  Kb + lin);
        }
        int s = tid & 127, dg = tid >> 7;
        const unsigned short* vsrc = vbase + (size_t)(kt * 128 + s) * rstr + dg * 16;
        union { i32x4 v; unsigned short u[8]; } v0, v1;
        v0.v = *(const i32x4*)vsrc;
        v1.v = *(const i32x4*)(vsrc + 8);
#pragma unroll
        for (int j = 0; j < 8; ++j) {
            int d = dg * 16 + j;
            *(unsigned short*)(Vb + d * 256 + ((s * 2) ^ ((d & 15) << 4))) = v0.u[j];
        }
#pragma unroll
        for (int j = 0; j < 8; ++j) {
            int d = dg * 16 + 8 + j;
            *(unsigned short*)(Vb + d * 256 + ((s * 2) ^ ((d & 15) << 4))) = v1.u[j];
        }
    };

    const float C   = 0.18033688f;   // log2e / sqrt(64)
    const float L2E = 1.44269504f;

    stage(0, 0);
    __syncthreads();

    for (int kt = 0; kt < 4; ++kt) {
        const int cur = kt & 1;
        if (kt < 3) stage(kt + 1, cur ^ 1);
        char* Kb = smem + cur * 16384;
        char* Vb = smem + 32768 + cur * 16384;
        const int swzk = (l31 & 7) << 4;

        // ---- QK^T: 4 tiles of 32 kpos ----
        f32x16 sc[4];
#pragma unroll
        for (int t = 0; t < 4; ++t) {
            f32x16 a = {};
#pragma unroll
            for (int kc = 0; kc < 4; ++kc) {
                s16x8 kf = *(const s16x8*)(Kb + (32 * t + l31) * 128 +
                                           ((kc * 32 + hi * 16) ^ swzk));
                a = __builtin_amdgcn_mfma_f32_32x32x16_bf16(kf, qf[kc], a, 0, 0, 0);
            }
            sc[t] = a;
        }

        // ---- scale + mask (global, broadcast), tile max ----
        float tm = -3e38f;
#pragma unroll
        for (int t = 0; t < 4; ++t) {
#pragma unroll
            for (int k2 = 0; k2 < 4; ++k2) {
                f32x4 mk = *(const f32x4*)(mrow + kt * 128 + 32 * t + 8 * k2 + 4 * hi);
#pragma unroll
                for (int i = 0; i < 4; ++i) {
                    float v = sc[t][4 * k2 + i] * C + mk[i] * L2E;
                    sc[t][4 * k2 + i] = v;
                    tm = fmaxf(tm, v);
                }
            }
        }
        tm = fmaxf(tm, __shfl_xor(tm, 32, 64));

        // ---- defer-max online softmax (rescale is rare) ----
        if (__any(tm > m + 11.0f)) {
            float mn = fmaxf(m, tm);
            float fac = exp2f(m - mn);
            m = mn;
            l *= fac;
            int fi = __float_as_int(fac);
#pragma unroll
            for (int r = 0; r < 16; ++r) {
                int q2 = (r & 3) + 8 * (r >> 2);
                float fq = __int_as_float(
                    __builtin_amdgcn_ds_bpermute(bpbase + q2 * 4, fi));
                O0[r] *= fq;
                O1[r] *= fq;
            }
        }

        float ts = 0.f;
#pragma unroll
        for (int t = 0; t < 4; ++t)
#pragma unroll
            for (int r = 0; r < 16; ++r) {
                float p = exp2f(sc[t][r] - m);
                sc[t][r] = p;
                ts += p;
            }
        ts += __shfl_xor(ts, 32, 64);
        l += ts;

        // ---- pack P to bf16 pairs (VALU only) ----
        unsigned pk01[4][4], pk23[4][4];
#pragma unroll
        for (int t = 0; t < 4; ++t)
#pragma unroll
            for (int k = 0; k < 4; ++k) {
                unsigned r0, r1;
                asm("v_cvt_pk_bf16_f32 %0, %1, %2"
                    : "=v"(r0) : "v"(sc[t][4 * k]), "v"(sc[t][4 * k + 1]));
                asm("v_cvt_pk_bf16_f32 %0, %1, %2"
                    : "=v"(r1) : "v"(sc[t][4 * k + 2]), "v"(sc[t][4 * k + 3]));
                pk01[t][k] = r0;
                pk23[t][k] = r1;
            }

        // ---- PV: per 16-kpos chunk assemble A-frag via permlane32_swap ----
#pragma unroll
        for (int t = 0; t < 4; ++t)
#pragma unroll
            for (int cc = 0; cc < 2; ++cc) {
                unsigned a0 = pk01[t][2 * cc], b0 = pk01[t][2 * cc + 1];
                unsigned c0 = pk23[t][2 * cc], d0 = pk23[t][2 * cc + 1];
                asm("v_permlane32_swap_b32 %0, %1" : "+v"(a0), "+v"(b0));
                asm("v_permlane32_swap_b32 %0, %1" : "+v"(c0), "+v"(d0));
                union { unsigned u[4]; s16x8 v; } pf;
                pf.u[0] = a0;  // w0: j0,1  (from lower half)
                pf.u[1] = c0;  // w1: j2,3  (from lower half)
                pf.u[2] = b0;  // w2: j4,5  (from upper half)
                pf.u[3] = d0;  // w3: j6,7  (from upper half)
                const int kc = 2 * t + cc;
                {
                    int row = l31;  // dt=0
                    s16x8 vf = *(const s16x8*)(Vb + row * 256 +
                               ((kc * 32 + hi * 16) ^ ((row & 15) << 4)));
                    O0 = __builtin_amdgcn_mfma_f32_32x32x16_bf16(pf.v, vf, O0, 0, 0, 0);
                }
                {
                    int row = 32 + l31;  // dt=1
                    s16x8 vf = *(const s16x8*)(Vb + row * 256 +
                               ((kc * 32 + hi * 16) ^ ((row & 15) << 4)));
                    O1 = __builtin_amdgcn_mfma_f32_32x32x16_bf16(pf.v, vf, O1, 0, 0, 0);
                }
            }
        __syncthreads();
    }

    // ---- epilogue: normalize by l (bpermute per output row) and store ----
    const int li = __float_as_int(l);
#pragma unroll
    for (int r = 0; r < 16; ++r) {
        int q2 = (r & 3) + 8 * (r >> 2);
        float lq = __int_as_float(__builtin_amdgcn_ds_bpermute(bpbase + q2 * 4, li));
        float inv = 1.f / lq;
        size_t rowg = (size_t)(b * 512 + qt + q2 + 4 * hi) * 1024 + h * 64;
        ctx[rowg + l31]      = f2bf(O0[r] * inv);
        ctx[rowg + 32 + l31] = f2bf(O1[r] * inv);
    }
}

// ---------------------------------------------------------------------------
// Launch. ws layout (bytes):
//   0          qkv bf16   [8192][3072]  50,331,648   (later overlaid by h)
//   50331648   y1 bf16    [8192][1024]  16,777,216
//   67108864   ctx/y2 bf16[8192][1024]  16,777,216
//   83886080   x2 fp32    [8192][1024]  33,554,432
//   117440512  bf16 weights (qkv_w, attn_ow, inter_w, out_w) 25,165,824
// ---------------------------------------------------------------------------
extern "C" void kernel_launch(void* const* d_in, const int* in_sizes, int n_in,
                              void* d_out, int out_size, void* d_ws, size_t ws_size,
                              hipStream_t stream) {
    const float* x    = (const float*)d_in[0];
    const float* mask = (const float*)d_in[1];
    const float* qkvw = (const float*)d_in[2];
    const float* qkvb = (const float*)d_in[3];
    const float* ow   = (const float*)d_in[4];
    const float* ob   = (const float*)d_in[5];
    const float* ln1g = (const float*)d_in[6];
    const float* ln1b = (const float*)d_in[7];
    const float* iw   = (const float*)d_in[8];
    const float* ib   = (const float*)d_in[9];
    const float* o2w  = (const float*)d_in[10];
    const float* o2b  = (const float*)d_in[11];
    const float* ln2g = (const float*)d_in[12];
    const float* ln2b = (const float*)d_in[13];

    char* ws = (char*)d_ws;
    unsigned short* qkvbuf = (unsigned short*)(ws);
    unsigned short* ybuf   = (unsigned short*)(ws + 50331648);
    unsigned short* cbuf   = (unsigned short*)(ws + 67108864);
    float*          x2     = (float*)(ws + 83886080);
    unsigned short* wq     = (unsigned short*)(ws + 117440512);
    unsigned short* wo     = (unsigned short*)(ws + 123731968);
    unsigned short* wi     = (unsigned short*)(ws + 125829120);
    unsigned short* wo2    = (unsigned short*)(ws + 134217728);
    unsigned short* hbuf   = (unsigned short*)(ws);  // overlays qkvbuf+ybuf

    wconv_kernel<<<12288, 256, 0, stream>>>(qkvw, ow, iw, o2w, wq, wo, wi, wo2);
    ln_kernel<<<8192, 256, 0, stream>>>(x, ln1g, ln1b, ybuf);
    gemm_bt<false, false, true><<<dim3(24, 64), 256, 0, stream>>>(
        ybuf, wq, qkvb, nullptr, qkvbuf, 8192, 3072, 1024);
    hipFuncSetAttribute(reinterpret_cast<const void*>(attn_kernel),
                        hipFuncAttributeMaxDynamicSharedMemorySize, 65536);
    attn_kernel<<<512, 512, 65536, stream>>>(qkvbuf, mask, cbuf);
    gemm_bt<false, true, false><<<dim3(8, 64), 256, 0, stream>>>(
        cbuf, wo, ob, x, x2, 8192, 1024, 1024);
    ln_kernel<<<8192, 256, 0, stream>>>(x2, ln2g, ln2b, cbuf);
    gemm_bt<true, false, true><<<dim3(32, 64), 256, 0, stream>>>(
        cbuf, wi, ib, nullptr, hbuf, 8192, 4096, 1024);
    gemm_bt<false, true, false><<<dim3(8, 64), 256, 0, stream>>>(
        hbuf, wo2, o2b, x2, (float*)d_out, 8192, 1024, 4096);
}